// Round 1
// baseline (312.168 us; speedup 1.0000x reference)
//
#include <hip/hip_runtime.h>

#define B_SZ 16384
#define D_SZ 256
#define C_SZ 2000
#define MARGIN_F 1.0f

// ---------------- gt kernel: one wave per row ----------------
// gt[b] = dot(pred[b, :], sig[:, label[b]])
__global__ __launch_bounds__(256) void gt_kernel(
    const float* __restrict__ pred, const float* __restrict__ sig,
    const int* __restrict__ label, float* __restrict__ gt) {
  int wave = (blockIdx.x * blockDim.x + threadIdx.x) >> 6;
  int lane = threadIdx.x & 63;
  if (wave >= B_SZ) return;
  int lbl = label[wave];
  const float* pr = pred + (size_t)wave * D_SZ;
  float s = 0.f;
#pragma unroll
  for (int d0 = 0; d0 < D_SZ; d0 += 64) {
    int d = d0 + lane;
    s += pr[d] * sig[(size_t)d * C_SZ + lbl];
  }
#pragma unroll
  for (int off = 32; off > 0; off >>= 1) s += __shfl_down(s, off, 64);
  if (lane == 0) gt[wave] = s;
}

// ---------------- fused GEMM + hinge + reduce ----------------
// 128x128 tile per block, BK=32, 256 threads, 8x8 per-thread register tile.
#define BM 128
#define BN 128
#define BK 32

__global__ __launch_bounds__(256) void fused_kernel(
    const float* __restrict__ pred, const float* __restrict__ sig,
    const int* __restrict__ label, const float* __restrict__ gt,
    float* __restrict__ out) {
  __shared__ float As[BK][BM + 4];  // +4 pad: breaks 128-stride bank conflicts
  __shared__ float Bs[BK][BN];

  int tid = threadIdx.x;
  int tileRow = (int)(blockIdx.x >> 4) * BM;   // 128 row tiles
  int tileCol = (int)(blockIdx.x & 15) * BN;   // 16 col tiles (last partial)

  int tx = tid & 15;   // 16 threads across N
  int ty = tid >> 4;   // 16 threads across M

  float acc[8][8] = {};

  for (int kk = 0; kk < D_SZ; kk += BK) {
    // Stage A tile: 128 rows x 32 k = 1024 float4, 4 per thread, coalesced on k
#pragma unroll
    for (int i = 0; i < 4; i++) {
      int idx = tid + i * 256;            // 0..1023
      int row = idx >> 3;                 // 8 float4 per row
      int kq  = (idx & 7) << 2;           // k offset (floats)
      float4 v = *(const float4*)(pred + (size_t)(tileRow + row) * D_SZ + kk + kq);
      As[kq + 0][row] = v.x;
      As[kq + 1][row] = v.y;
      As[kq + 2][row] = v.z;
      As[kq + 3][row] = v.w;
    }
    // Stage B tile: 32 k x 128 cols = 1024 float4, coalesced on cols
#pragma unroll
    for (int i = 0; i < 4; i++) {
      int idx = tid + i * 256;
      int k    = idx >> 5;                // 32 float4 per k-row
      int colq = (idx & 31) << 2;
      int col  = tileCol + colq;
      float4 v = make_float4(0.f, 0.f, 0.f, 0.f);
      if (col < C_SZ)                     // C%4==0 so float4 fully in/out
        v = *(const float4*)(sig + (size_t)(kk + k) * C_SZ + col);
      *(float4*)&Bs[k][colq] = v;
    }
    __syncthreads();

#pragma unroll
    for (int k = 0; k < BK; k++) {
      float a[8], b[8];
      *(float4*)&a[0] = *(const float4*)&As[k][ty * 8];
      *(float4*)&a[4] = *(const float4*)&As[k][ty * 8 + 4];
      *(float4*)&b[0] = *(const float4*)&Bs[k][tx * 8];
      *(float4*)&b[4] = *(const float4*)&Bs[k][tx * 8 + 4];
#pragma unroll
      for (int i = 0; i < 8; i++)
#pragma unroll
        for (int j = 0; j < 8; j++) acc[i][j] += a[i] * b[j];
    }
    __syncthreads();
  }

  // Epilogue: hinge + mask + per-thread partial sum
  float sum = 0.f;
#pragma unroll
  for (int i = 0; i < 8; i++) {
    int row = tileRow + ty * 8 + i;
    float g = gt[row];
    int lbl = label[row];
#pragma unroll
    for (int j = 0; j < 8; j++) {
      int col = tileCol + tx * 8 + j;
      if (col < C_SZ && col != lbl) {
        float h = MARGIN_F + acc[i][j] - g;
        sum += (h > 0.f) ? h : 0.f;
      }
    }
  }

  // wave reduce then block reduce, one atomic per block
#pragma unroll
  for (int off = 32; off > 0; off >>= 1) sum += __shfl_down(sum, off, 64);
  __shared__ float red[4];
  int lane = tid & 63, wv = tid >> 6;
  if (lane == 0) red[wv] = sum;
  __syncthreads();
  if (tid == 0) atomicAdd(out, red[0] + red[1] + red[2] + red[3]);
}

extern "C" void kernel_launch(void* const* d_in, const int* in_sizes, int n_in,
                              void* d_out, int out_size, void* d_ws, size_t ws_size,
                              hipStream_t stream) {
  const float* pred  = (const float*)d_in[0];   // (B, D) fp32
  const int*   label = (const int*)d_in[1];     // (B,) int
  // d_in[2] = train_classes = arange(C) — identity, unused
  const float* sig   = (const float*)d_in[3];   // (D, C) fp32
  float* out = (float*)d_out;
  float* gt  = (float*)d_ws;                    // B floats of scratch

  hipMemsetAsync(out, 0, sizeof(float), stream);
  gt_kernel<<<B_SZ / 4, 256, 0, stream>>>(pred, sig, label, gt);
  fused_kernel<<<(B_SZ / BM) * ((C_SZ + BN - 1) / BN), 256, 0, stream>>>(
      pred, sig, label, gt, out);
}

// Round 2
// 119.889 us; speedup vs baseline: 2.6038x; 2.6038x over previous
//
#include <hip/hip_runtime.h>

#define B_SZ 16384
#define D_SZ 256
#define C_SZ 2000
#define C_PAD 2048
#define MARGIN_F 1.0f

typedef __bf16 bf16x8 __attribute__((ext_vector_type(8)));
typedef __bf16 bf16x4 __attribute__((ext_vector_type(4)));
typedef float floatx4 __attribute__((ext_vector_type(4)));

__device__ inline void gld_lds16(const void* g, void* l) {
  __builtin_amdgcn_global_load_lds(
      (const __attribute__((address_space(1))) void*)g,
      (__attribute__((address_space(3))) void*)l, 16, 0, 0);
}

// ---- pred fp32 -> bf16 (8 elems/thread) ----
__global__ __launch_bounds__(256) void convert_pred_kernel(
    const float* __restrict__ in, __bf16* __restrict__ out) {
  int idx = (blockIdx.x * 256 + threadIdx.x) * 8;
  float4 v0 = *(const float4*)(in + idx);
  float4 v1 = *(const float4*)(in + idx + 4);
  bf16x8 o;
  o[0] = (__bf16)v0.x; o[1] = (__bf16)v0.y; o[2] = (__bf16)v0.z; o[3] = (__bf16)v0.w;
  o[4] = (__bf16)v1.x; o[5] = (__bf16)v1.y; o[6] = (__bf16)v1.z; o[7] = (__bf16)v1.w;
  *(bf16x8*)(out + idx) = o;
}

// ---- sig (D x C) fp32 -> sigT (C_PAD x D) bf16, zero-padded cols >= C ----
__global__ __launch_bounds__(256) void convert_sigT_kernel(
    const float* __restrict__ sig, __bf16* __restrict__ sigT) {
  int t = blockIdx.x * 256 + threadIdx.x;  // 65536 threads
  int c = t >> 5;                          // 32 threads per class row
  int d0 = (t & 31) * 8;
  bf16x8 o;
  if (c < C_SZ) {
#pragma unroll
    for (int i = 0; i < 8; i++) o[i] = (__bf16)sig[(size_t)(d0 + i) * C_SZ + c];
  } else {
#pragma unroll
    for (int i = 0; i < 8; i++) o[i] = (__bf16)0.f;
  }
  *(bf16x8*)(sigT + (size_t)c * D_SZ + d0) = o;
}

// ---- gt[b] = dot(predb[b,:], sigT[label[b],:]) — one wave per row ----
__global__ __launch_bounds__(256) void gt_kernel(
    const __bf16* __restrict__ predb, const __bf16* __restrict__ sigT,
    const int* __restrict__ label, float* __restrict__ gt) {
  int row = (blockIdx.x * 256 + threadIdx.x) >> 6;
  int lane = threadIdx.x & 63;
  int lbl = label[row];
  bf16x4 p = *(const bf16x4*)(predb + (size_t)row * D_SZ + lane * 4);
  bf16x4 s = *(const bf16x4*)(sigT + (size_t)lbl * D_SZ + lane * 4);
  float sum = 0.f;
#pragma unroll
  for (int i = 0; i < 4; i++) sum += (float)p[i] * (float)s[i];
#pragma unroll
  for (int off = 32; off > 0; off >>= 1) sum += __shfl_down(sum, off, 64);
  if (lane == 0) gt[row] = sum;
}

// ---- fused MFMA GEMM + hinge + reduce ----
// 128x128 tile, BK=32, 4 waves each computing 64x64 (4x4 MFMA 16x16x32 tiles)
__global__ __launch_bounds__(256) void mfma_fused_kernel(
    const __bf16* __restrict__ A,   // predb [B_SZ][D_SZ]
    const __bf16* __restrict__ Bt,  // sigT  [C_PAD][D_SZ]
    const int* __restrict__ label, const float* __restrict__ gt,
    float* __restrict__ out) {
  __shared__ __bf16 As[128 * 32];
  __shared__ __bf16 Bs[128 * 32];
  __shared__ float gtS[128];
  __shared__ int lblS[128];
  __shared__ float red[4];

  int tid = threadIdx.x;
  int lane = tid & 63;
  int w = tid >> 6;
  int wy = w >> 1, wx = w & 1;
  int quad = lane >> 4, lm = lane & 15;
  int tileRow = (int)(blockIdx.x >> 4) * 128;
  int tileCol = (int)(blockIdx.x & 15) * 128;

  if (tid < 128) {
    gtS[tid] = gt[tileRow + tid];
    lblS[tid] = label[tileRow + tid];
  }

  floatx4 acc[4][4] = {};

  for (int kk = 0; kk < D_SZ; kk += 32) {
    // stage: each wave 2x A-chunks + 2x B-chunks of 64 lanes x 16B
#pragma unroll
    for (int i = 0; i < 2; i++) {
      int q = w * 128 + i * 64 + lane;   // chunk id 0..511
      int row = q >> 2, k8 = q & 3;      // 4 x 16B chunks per 32-elem row
      gld_lds16(A + (size_t)(tileRow + row) * D_SZ + kk + k8 * 8,
                (void*)(As + (w * 128 + i * 64) * 8));
      gld_lds16(Bt + (size_t)(tileCol + row) * D_SZ + kk + k8 * 8,
                (void*)(Bs + (w * 128 + i * 64) * 8));
    }
    __syncthreads();

    bf16x8 af[4], bf[4];
#pragma unroll
    for (int i = 0; i < 4; i++) {
      af[i] = *(const bf16x8*)(As + ((wy * 64 + i * 16 + lm) * 32 + quad * 8));
      bf[i] = *(const bf16x8*)(Bs + ((wx * 64 + i * 16 + lm) * 32 + quad * 8));
    }
#pragma unroll
    for (int i = 0; i < 4; i++)
#pragma unroll
      for (int j = 0; j < 4; j++)
        acc[i][j] = __builtin_amdgcn_mfma_f32_16x16x32_bf16(af[i], bf[j], acc[i][j], 0, 0, 0);
    __syncthreads();
  }

  // epilogue: hinge + mask; C/D layout col=lane&15, row=quad*4+reg
  float sum = 0.f;
#pragma unroll
  for (int i = 0; i < 4; i++) {
#pragma unroll
    for (int r = 0; r < 4; r++) {
      int lrow = wy * 64 + i * 16 + quad * 4 + r;
      float g = gtS[lrow];
      int lbl = lblS[lrow];
#pragma unroll
      for (int j = 0; j < 4; j++) {
        int col = tileCol + wx * 64 + j * 16 + lm;
        if (col < C_SZ && col != lbl) {
          float h = MARGIN_F + acc[i][j][r] - g;
          sum += fmaxf(h, 0.f);
        }
      }
    }
  }
#pragma unroll
  for (int off = 32; off > 0; off >>= 1) sum += __shfl_down(sum, off, 64);
  if (lane == 0) red[w] = sum;
  __syncthreads();
  if (tid == 0) atomicAdd(out, red[0] + red[1] + red[2] + red[3]);
}

extern "C" void kernel_launch(void* const* d_in, const int* in_sizes, int n_in,
                              void* d_out, int out_size, void* d_ws, size_t ws_size,
                              hipStream_t stream) {
  const float* pred  = (const float*)d_in[0];   // (B, D) fp32
  const int*   label = (const int*)d_in[1];     // (B,) int
  // d_in[2] = train_classes = arange(C), unused
  const float* sig   = (const float*)d_in[3];   // (D, C) fp32
  float* out = (float*)d_out;

  float*  gt    = (float*)d_ws;                                  // 64 KB
  __bf16* predb = (__bf16*)((char*)d_ws + (64 << 10));           // 8 MB
  __bf16* sigT  = (__bf16*)((char*)d_ws + (64 << 10) + (8 << 20));// 1 MB

  hipMemsetAsync(out, 0, sizeof(float), stream);
  convert_pred_kernel<<<B_SZ * D_SZ / 8 / 256, 256, 0, stream>>>(pred, predb);
  convert_sigT_kernel<<<C_PAD * D_SZ / 8 / 256, 256, 0, stream>>>(sig, sigT);
  gt_kernel<<<B_SZ / 4, 256, 0, stream>>>(predb, sigT, label, gt);
  mfma_fused_kernel<<<(B_SZ / 128) * (C_PAD / 128), 256, 0, stream>>>(
      predb, sigT, label, gt, out);
}